// Round 1
// baseline (139.093 us; speedup 1.0000x reference)
//
#include <hip/hip_runtime.h>
#include <math.h>

// L = 2*pi * log2(e): folds the exp->exp2 conversion into the point prep.
#define LCONST 9.064720283654388f

__device__ __forceinline__ float fexp2(float x) {
#if defined(__has_builtin)
#if __has_builtin(__builtin_amdgcn_exp2f)
    return __builtin_amdgcn_exp2f(x);
#else
    return exp2f(x);
#endif
#else
    return exp2f(x);
#endif
}

// Prep: P1[t] = (x,y,z, -L*|p|^2) for C1 points; PD[t] = (2L*dx,2L*dy,2L*dz, -L*|d|^2)
// for dom points; PC likewise for C points; zero the prod accumulator.
__global__ void k_prep(const float* __restrict__ C1, const float* __restrict__ C,
                       const float* __restrict__ dom,
                       float4* __restrict__ P1, float4* __restrict__ PD,
                       float4* __restrict__ PC, float* __restrict__ prod) {
    int t = blockIdx.x * blockDim.x + threadIdx.x;  // 0..16383
    {
        float x = C1[3*t], y = C1[3*t+1], z = C1[3*t+2];
        float q = -LCONST * (x*x + y*y + z*z);
        P1[t] = make_float4(x, y, z, q);
    }
    {
        float x = dom[3*t], y = dom[3*t+1], z = dom[3*t+2];
        float base = -LCONST * (x*x + y*y + z*z);
        PD[t] = make_float4(2.0f*LCONST*x, 2.0f*LCONST*y, 2.0f*LCONST*z, base);
    }
    if (t < 1024) {
        float x = C[3*t], y = C[3*t+1], z = C[3*t+2];
        float q = -LCONST * (x*x + y*y + z*z);
        PC[t] = make_float4(x, y, z, q);
    }
    if (t < 16) prod[t] = 0.0f;
}

// theta_C, split 4-ways over the 1024 C points for occupancy.
// TCp[q*16384 + k] = sum over n in [256q, 256q+256).
__global__ void __launch_bounds__(256) k_tc(const float4* __restrict__ PD,
                                            const float4* __restrict__ PC,
                                            float* __restrict__ TCp) {
    int t = blockIdx.x * blockDim.x + threadIdx.x;  // 0..65535
    int k = t & 16383;
    int q = t >> 14;   // uniform per block (64 blocks per q)
    float4 d = PD[k];
    const float4* P = PC + (q << 8);
    float acc = 0.0f;
    #pragma unroll 8
    for (int n = 0; n < 256; ++n) {
        float4 p = P[n];
        float arg = fmaf(d.x, p.x, fmaf(d.y, p.y, fmaf(d.z, p.z, d.w + p.w)));
        acc += fexp2(arg);
    }
    TCp[t] = acc;
}

// Main: thread = grid point k, block-uniform batch b. 1024-iteration inner loop,
// wave-uniform point loads. Block reduce theta_b[k]*theta_C[k], one atomic per block.
__global__ void __launch_bounds__(256) k_main(const float4* __restrict__ PD,
                                              const float4* __restrict__ P1,
                                              const float* __restrict__ TCp,
                                              float* __restrict__ prod) {
    int b = blockIdx.y;
    int k = blockIdx.x * blockDim.x + threadIdx.x;  // 0..16383
    float4 d = PD[k];
    const float4* Pb = P1 + (b << 10);
    float acc = 0.0f;
    #pragma unroll 8
    for (int n = 0; n < 1024; ++n) {
        float4 p = Pb[n];
        float arg = fmaf(d.x, p.x, fmaf(d.y, p.y, fmaf(d.z, p.z, d.w + p.w)));
        acc += fexp2(arg);
    }
    float tc = TCp[k] + TCp[16384 + k] + TCp[32768 + k] + TCp[49152 + k];
    float v = acc * tc;
    // wave64 reduce
    for (int off = 32; off; off >>= 1) v += __shfl_down(v, off, 64);
    __shared__ float wsum[4];
    int lane = threadIdx.x & 63, wid = threadIdx.x >> 6;
    if (lane == 0) wsum[wid] = v;
    __syncthreads();
    if (threadIdx.x == 0)
        atomicAdd(prod + b, wsum[0] + wsum[1] + wsum[2] + wsum[3]);
}

__global__ void k_final(const float* __restrict__ prod, float* __restrict__ out) {
    int t = threadIdx.x;
    if (t < 16) {
        const float scale = 4.76837158203125e-4f;  // A * V / 1024 = 8*(1000/16384)/1024
        float dot = prod[t] * scale;
        dot = fminf(fmaxf(dot, 0.0f), 1.0f);
        out[t] = 1.0f - dot;
    }
}

extern "C" void kernel_launch(void* const* d_in, const int* in_sizes, int n_in,
                              void* d_out, int out_size, void* d_ws, size_t ws_size,
                              hipStream_t stream) {
    const float* C1  = (const float*)d_in[0];   // (16,1024,3)
    const float* C   = (const float*)d_in[1];   // (1024,3)
    const float* dom = (const float*)d_in[2];   // (16384,3)
    float* out = (float*)d_out;                 // (16,)

    char* ws = (char*)d_ws;
    float4* PD  = (float4*)(ws + 0);        // 16384 * 16B = 262144
    float4* P1  = (float4*)(ws + 262144);   // 16384 * 16B -> ends 524288
    float4* PC  = (float4*)(ws + 524288);   // 1024 * 16B  -> ends 540672
    float*  TCp = (float*)(ws + 540672);    // 4*16384 * 4B -> ends 802816
    float*  prod= (float*)(ws + 802816);    // 16 floats    -> ends 802880

    k_prep<<<64, 256, 0, stream>>>(C1, C, dom, P1, PD, PC, prod);
    k_tc<<<256, 256, 0, stream>>>(PD, PC, TCp);
    k_main<<<dim3(64, 16), 256, 0, stream>>>(PD, P1, TCp, prod);
    k_final<<<1, 64, 0, stream>>>(prod, out);
}